// Round 7
// baseline (255.587 us; speedup 1.0000x reference)
//
#include <hip/hip_runtime.h>

// Problem constants: h[B,G,D], W[G,D,K], out[B,G,K]
#define Gn   100
#define Bn   256
#define Dn   768
#define Kn   128
#define LDP  36   // LDS leading dim in shorts (32+4): 72 B row stride -> the 16
                  // frag-read rows hit 16 DISTINCT bank-quad starts (optimal)

typedef __attribute__((ext_vector_type(8))) short short8;
typedef __attribute__((ext_vector_type(4))) float f32x4;

// pack two fp32 -> two bf16 (round-to-nearest, ties away) in 3 VALU
__device__ inline unsigned pack2(float lo, float hi) {
  union { float f; unsigned u; } a, b; a.f = lo; b.f = hi;
  return __builtin_amdgcn_perm(b.u + 0x8000u, a.u + 0x8000u, 0x07060302u);
}

// Non-draining block barrier (R6): skip the vmcnt(0) drain; global loads here
// only target per-wave-private registers, LDS visibility via lgkmcnt(0).
__device__ inline void barrier_nodrain() {
  asm volatile("s_waitcnt lgkmcnt(0)\n\ts_barrier" ::: "memory");
}

// Fused grouped GEMM, 128x128 tile (halves CU-side vmem bytes vs 64x64 —
// the measured ~10 B/cyc/CU vmem ceiling is the binding constraint across
// R1-R6). 4 waves (2x2), each owns a 64x64 sub-tile: 16 accs, 16 MFMA +
// 8 ds_read_b128 per BK=32 step. Register staging, triple-buffered LDS,
// one nodrain barrier per K-step, 2-deep register prefetch.
// grid 208 = 26*8; XCD swizzle: id%8 == g%8 (R5: FETCH 154->57 MB).
__global__ __launch_bounds__(256) void groupfc_kernel(
    const float* __restrict__ h, const float* __restrict__ W,
    float* __restrict__ out) {
  const int id  = blockIdx.x;
  const int xcd = id & 7;
  const int q   = id >> 3;                   // 0..25
  const int g   = (q >> 1) * 8 + xcd;        // g % 8 == xcd
  if (g >= Gn) return;                       // 8 pad blocks exit
  const int mt  = q & 1;                     // 0..1 (rows of 128)

  const int t    = threadIdx.x;
  const int lane = t & 63;
  const int wave = t >> 6;
  const int wm   = wave >> 1, wn = wave & 1; // 2x2 wave grid, 64x64 each
  const int l15  = lane & 15, quad = lane >> 4;

  __shared__ __align__(16) short Af[3][128 * LDP];   // [m][k] bf16
  __shared__ __align__(16) short Bf[3][128 * LDP];   // [n][k] bf16 (W transposed)
  __shared__ float AssqL[128];
  __shared__ float BssqL[2][128];

  f32x4 acc[4][4];
#pragma unroll
  for (int i = 0; i < 4; ++i)
#pragma unroll
    for (int j = 0; j < 4; ++j) acc[i][j] = f32x4{0.f, 0.f, 0.f, 0.f};

  // A staging: thread -> (row ar = t>>1, 16 contiguous k at ac)
  const int ar = t >> 1;
  const int ac = (t & 1) * 16;
  const float* aptr = h + ((size_t)(mt * 128 + ar) * Gn + g) * Dn + ac;
  // B staging: thread -> (col bn = t&127, 16 k at bq*16); coalesced across bn
  const int bn = t & 127;
  const int bq = t >> 7;                     // 0..1
  const float* bptr = W + (size_t)g * (Dn * Kn) + (size_t)(bq * 16) * Kn + bn;

  const int koff = quad * 8;                 // A/B fragment: k = quad*8 + j

  float assq = 0.f, bssq = 0.f;
  float4 Ar[2][4];                           // 2 in-flight chunk sets
  float  Br[2][16];

  auto load_set = [&](int c, int s) {        // issue chunk-c loads into set s
    const int d0 = c * 32;
#pragma unroll
    for (int i = 0; i < 4; ++i) Ar[s][i] = *(const float4*)(aptr + d0 + i * 4);
#pragma unroll
    for (int i = 0; i < 16; ++i) Br[s][i] = bptr[(size_t)(d0 + i) * Kn];
  };

  auto pack_set = [&](int c, int s) {        // fp32 ssq + bf16 pack -> buf c%3
    const int b = c % 3;
    uint4 ap0, ap1;
    ap0.x = pack2(Ar[s][0].x, Ar[s][0].y); ap0.y = pack2(Ar[s][0].z, Ar[s][0].w);
    ap0.z = pack2(Ar[s][1].x, Ar[s][1].y); ap0.w = pack2(Ar[s][1].z, Ar[s][1].w);
    ap1.x = pack2(Ar[s][2].x, Ar[s][2].y); ap1.y = pack2(Ar[s][2].z, Ar[s][2].w);
    ap1.z = pack2(Ar[s][3].x, Ar[s][3].y); ap1.w = pack2(Ar[s][3].z, Ar[s][3].w);
#pragma unroll
    for (int i = 0; i < 4; ++i) {
      const float4 v = Ar[s][i];
      assq += v.x*v.x + v.y*v.y + v.z*v.z + v.w*v.w;
    }
    *(uint4*)&Af[b][ar * LDP + ac]     = ap0;
    *(uint4*)&Af[b][ar * LDP + ac + 8] = ap1;

    uint4 bp0, bp1;
    bp0.x = pack2(Br[s][0],  Br[s][1]);  bp0.y = pack2(Br[s][2],  Br[s][3]);
    bp0.z = pack2(Br[s][4],  Br[s][5]);  bp0.w = pack2(Br[s][6],  Br[s][7]);
    bp1.x = pack2(Br[s][8],  Br[s][9]);  bp1.y = pack2(Br[s][10], Br[s][11]);
    bp1.z = pack2(Br[s][12], Br[s][13]); bp1.w = pack2(Br[s][14], Br[s][15]);
#pragma unroll
    for (int i = 0; i < 16; ++i) bssq += Br[s][i] * Br[s][i];
    *(uint4*)&Bf[b][bn * LDP + bq * 16]     = bp0;
    *(uint4*)&Bf[b][bn * LDP + bq * 16 + 8] = bp1;
  };

  // ---- prologue: chunks 0,1 in flight; pack 0 -> buf 0 ----
  load_set(0, 0);
  load_set(1, 1);
  pack_set(0, 0);

  // ---- main loop: 24 K-steps (BK=32), one nodrain barrier each ----
  // Window [bar(c), bar(c+1)]: reads buf c%3, writes buf (c+2)%3 — disjoint.
  for (int c = 0; c < 24; ++c) {
    if (c + 2 < 24) load_set(c + 2, c & 1);
    if (c + 1 < 24) pack_set(c + 1, (c + 1) & 1);
    barrier_nodrain();

    const int b = c % 3;
    short8 af[4], bf[4];
#pragma unroll
    for (int i = 0; i < 4; ++i) {
      af[i] = *(const short8*)&Af[b][(wm * 64 + i * 16 + l15) * LDP + koff];
      bf[i] = *(const short8*)&Bf[b][(wn * 64 + i * 16 + l15) * LDP + koff];
    }
#pragma unroll
    for (int i = 0; i < 4; ++i)
#pragma unroll
      for (int j = 0; j < 4; ++j)
        acc[i][j] = __builtin_amdgcn_mfma_f32_16x16x32_bf16(af[i], bf[j], acc[i][j], 0, 0, 0);
  }

  // ---- block-reduce the norms ----
  assq += __shfl_xor(assq, 1);               // t and t^1 share row ar
  if ((t & 1) == 0) AssqL[ar] = assq;
  BssqL[bq][bn] = bssq;                      // 2 threads (bq) share col bn
  __syncthreads();                           // loop done: draining barrier fine

  // ---- epilogue: scale by 1/max(||h_row||,eps) * 1/max(||w_col||,eps) ----
  // C/D layout: col = lane&15, row = quad*4 + reg
  float wi[4];
#pragma unroll
  for (int j = 0; j < 4; ++j) {
    const int n = wn * 64 + j * 16 + l15;
    wi[j] = 1.0f / fmaxf(sqrtf(BssqL[0][n] + BssqL[1][n]), 1e-12f);
  }
#pragma unroll
  for (int i = 0; i < 4; ++i) {
#pragma unroll
    for (int r = 0; r < 4; ++r) {
      const int lr = wm * 64 + i * 16 + quad * 4 + r;    // local row in tile
      const float hs = 1.0f / fmaxf(sqrtf(AssqL[lr]), 1e-12f);
      const size_t ob = ((size_t)(mt * 128 + lr) * Gn + g) * Kn;
#pragma unroll
      for (int j = 0; j < 4; ++j)
        out[ob + wn * 64 + j * 16 + l15] = acc[i][j][r] * hs * wi[j];
    }
  }
}

extern "C" void kernel_launch(void* const* d_in, const int* in_sizes, int n_in,
                              void* d_out, int out_size, void* d_ws, size_t ws_size,
                              hipStream_t stream) {
  const float* h = (const float*)d_in[0];          // [B,G,D]
  const float* W = (const float*)d_in[1];          // [G,D,K]
  float* out = (float*)d_out;                      // [B,G,K]
  hipLaunchKernelGGL(groupfc_kernel, dim3(208), dim3(256), 0, stream, h, W, out);
}